// Round 9
// baseline (976.336 us; speedup 1.0000x reference)
//
#include <hip/hip_runtime.h>
#include <hip/hip_bf16.h>

// MI355X / gfx950. B=4,S=1024,D=1024,H=8,DK=DV=128,DFF=2048,L=2.
// FP32 in/out. bf16x2-split MFMA (hi*hi + hi*lo + lo*hi) for ~1e-5 relative
// accuracy (unscaled QK^T, score std ~20, sharp softmax).
// Round 15 (two changes on the R8 base, which is kept otherwise verbatim):
//  1) gemm_bt: XCD-chunked tile swizzle (bijective: all x*y grids div by 8;
//     z-planes keep mod-8 phase since x*y ≡ 0 mod 8). R8 PMC: FETCH 78 MB vs
//     28 MB ideal -> round-robin XCD assignment thrashes per-XCD L2 on A/B
//     panels. Chunking gives each XCD contiguous tile runs (A stays hot).
//  2) attn: V read direct-to-register from VT (B-fragment = 8 contiguous
//     bf16 at VT[bh][on*16+l16][t0+k2*32+quad*8]) — drops Vsh/Vsl staging,
//     LDS 73->41 KiB -> 3 blocks/CU (12 waves/CU), loop is 2 barriers:
//     vmcnt(0); barA; QK+softmax; lgkm(0); barB; stageK(t+1); PV(direct V).
//     K[t+1] hides under PV; V redundancy is L2-served (32KB/tile shared by
//     16 blocks per bh).
// GEMM core unchanged from R6/R8 best: 8-wave 128² tile, dbuf LDS, counted
// vmcnt(4), 88 µs QKV @ MfmaUtil 38 (~96% of this structure's ceiling).
// Split-K2 proj/FFN2 + 3-input LN kept (R3 win).
// Verified MFMA layouts: A[m=lane&15][k=quad*8+j], C/D col=lane&15,row=quad*4+reg.
// Staging swizzle: LDS slot (row, c) holds global chunk c ^ ((row>>1)&3);
// frag read offset = R*32 + ((quad ^ ((R>>1)&3))*8). Bank-conflict-free (proven).

typedef __bf16 bf16_t;
typedef bf16_t bf16x8 __attribute__((ext_vector_type(8)));
typedef bf16_t bf16x4v __attribute__((ext_vector_type(4)));
typedef float f32x4 __attribute__((ext_vector_type(4)));

#define MFMA16(a, b, c) __builtin_amdgcn_mfma_f32_16x16x32_bf16((a), (b), (c), 0, 0, 0)

__device__ __align__(256) unsigned char g_ws[(size_t)192 << 20];

#define MBOFF(x) ((size_t)(x) << 20)
#define OFF_X32 MBOFF(0)        // fp32 running residual (4M floats)
#define OFF_XB_HI MBOFF(16)     // bf16 hi/lo of x (GEMM A input)
#define OFF_XB_LO MBOFF(24)
#define OFF_QKV_HI MBOFF(32)    // fused QKV out [4096][3072]
#define OFF_QKV_LO MBOFF(56)
#define OFF_VT_HI MBOFF(80)     // V transposed [bh,v,s]
#define OFF_VT_LO MBOFF(88)
#define OFF_CONC_HI MBOFF(96)   // attention output [b,s,h*128+v]
#define OFF_CONC_LO MBOFF(104)
#define OFF_TMP MBOFF(112)      // fp32 proj/ffn2 slice-0 output (4M floats)
#define OFF_H_HI MBOFF(128)     // ffn hidden (4096x2048)
#define OFF_H_LO MBOFF(144)
#define OFF_WQKV_HI MBOFF(160)  // [3072][1024]
#define OFF_WQKV_LO MBOFF(166)
#define OFF_WO_HI MBOFF(172)
#define OFF_WO_LO MBOFF(174)
#define OFF_W1_HI MBOFF(176)
#define OFF_W1_LO MBOFF(180)
#define OFF_W2_HI MBOFF(184)
#define OFF_W2_LO MBOFF(188)
// split-K slice-1 fp32 partial. Aliases QKV_HI: QKV is dead from the proj GEMM
// (attn+vt_trans already consumed it) until the next layer's QKV GEMM, which
// runs after ln2 has read TMP2. Stream-ordered, so safe.
#define OFF_TMP2 MBOFF(32)

__device__ __forceinline__ void split2(float v, bf16_t& h, bf16_t& l) {
  h = (bf16_t)v;
  l = (bf16_t)(v - (float)h);
}

// async global->LDS, 16 bytes per lane; LDS dest = wave-uniform base + lane*16
__device__ __forceinline__ void gl2lds16(const bf16_t* g, bf16_t* l) {
  __builtin_amdgcn_global_load_lds(
      (const __attribute__((address_space(1))) unsigned int*)(g),
      (__attribute__((address_space(3))) unsigned int*)(l), 16, 0, 0);
}

// ---------------------------------------------------------------------------
// Split GEMM: C[M,N] = A[M,Ksl] @ Bt[N,Ksl]^T, (hi,lo) bf16 pairs.
// 128x128 tile, BK=32, 512 threads (8 waves). Wave w: m-group (w&3)*32,
// n-group (w>>2)*64. Double-buffered LDS + counted-vmcnt prefetch:
//   iter t: STAGE(nxt, t+1); vmcnt(4); s_barrier; sched_barrier(0);
//           ds_read + 24 MFMA (compiler-interleaved); lgkmcnt(0); s_barrier.
// Per-wave vmcnt audit: steady state has 8 outstanding gl2lds (4 of t, 4 of
// t+1); vmcnt(4) waits exactly t's. End-of-iter lgkmcnt(0)+barrier makes all
// reads of buf[cur] retire before iter t+1 overwrites it. Last iter vmcnt(0).
// XCD-chunked swizzle: hw linear id h (x fastest; XCD = h%8) computes tile
// (h%8)*cpx + h/8, so each XCD works a contiguous tile run (L2 locality).
// Bijective because gridDim.x*gridDim.y % 8 == 0 at every call site.
// Split-K via blockIdx.z: K-range [z*Ksl, (z+1)*Ksl); fp32 epilogues write to
// c0o (z=0) or c1o (z=1); bias applied on z==0 only.
// EPI: 0 = fp32 out, 1 = split out, 2 = split out + bias + relu, 3 = fp32+bias
// ---------------------------------------------------------------------------
template <int EPI>
__global__ __launch_bounds__(512) void gemm_bt(
    size_t a_hi, size_t a_lo, size_t b_hi, size_t b_lo,
    size_t c0o, size_t c1o, const float* __restrict__ bias,
    int M, int N, int Ktot, int Ksl) {
  const bf16_t* Ah = (const bf16_t*)(g_ws + a_hi);
  const bf16_t* Al = (const bf16_t*)(g_ws + a_lo);
  const bf16_t* Bh = (const bf16_t*)(g_ws + b_hi);
  const bf16_t* Bl = (const bf16_t*)(g_ws + b_lo);
  __shared__ __align__(16) bf16_t Ash[2][128 * 32];
  __shared__ __align__(16) bf16_t Asl[2][128 * 32];
  __shared__ __align__(16) bf16_t Bsh[2][128 * 32];
  __shared__ __align__(16) bf16_t Bsl[2][128 * 32];
  const int tid = threadIdx.x;
  const int wave = tid >> 6, lane = tid & 63;
  const int quad = lane >> 4, l16 = lane & 15;
  const int wm = wave & 3, wn = wave >> 2;
  // XCD-chunked tile swizzle (see header)
  const int gx = gridDim.x;
  int lid = blockIdx.y * gx + blockIdx.x;
  const int cpx = (gx * gridDim.y) >> 3;
  lid = (lid & 7) * cpx + (lid >> 3);
  const int m0 = (lid / gx) * 128, n0 = (lid % gx) * 128;
  const int z = blockIdx.z;
  // staging: wave covers rows wave*16..+15, lane -> (row lane>>2, chunk lane&3)
  const int srow = wave * 16 + (lane >> 2);
  const int scp = (lane & 3) ^ ((srow >> 1) & 3);
  const long agoff = (long)(m0 + srow) * Ktot + (long)z * Ksl + scp * 8;
  const long bgoff = (long)(n0 + srow) * Ktot + (long)z * Ksl + scp * 8;
  const int ldsw = wave * 512;  // wave's 16 rows * 32 elems
  // frag read offsets (swizzled)
  int aOff[2], bOff[4];
#pragma unroll
  for (int mt = 0; mt < 2; ++mt) {
    int R = wm * 32 + mt * 16 + l16;
    aOff[mt] = R * 32 + ((quad ^ ((R >> 1) & 3)) * 8);
  }
#pragma unroll
  for (int nt = 0; nt < 4; ++nt) {
    int R = wn * 64 + nt * 16 + l16;
    bOff[nt] = R * 32 + ((quad ^ ((R >> 1) & 3)) * 8);
  }
  f32x4 acc[2][4] = {};
  const int nk = Ksl >> 5;

  // prologue: stage tile 0 into buffer 0 (4 gl2lds per wave)
  gl2lds16(Ah + agoff, &Ash[0][ldsw]);
  gl2lds16(Al + agoff, &Asl[0][ldsw]);
  gl2lds16(Bh + bgoff, &Bsh[0][ldsw]);
  gl2lds16(Bl + bgoff, &Bsl[0][ldsw]);

  for (int t = 0; t < nk; ++t) {
    const int cur = t & 1, nxt = cur ^ 1;
    const long ko = (long)(t + 1) * 32;
    if (t + 1 < nk) {
      gl2lds16(Ah + agoff + ko, &Ash[nxt][ldsw]);
      gl2lds16(Al + agoff + ko, &Asl[nxt][ldsw]);
      gl2lds16(Bh + bgoff + ko, &Bsh[nxt][ldsw]);
      gl2lds16(Bl + bgoff + ko, &Bsl[nxt][ldsw]);
      asm volatile("s_waitcnt vmcnt(4)" ::: "memory");  // tile t landed
    } else {
      asm volatile("s_waitcnt vmcnt(0)" ::: "memory");
    }
    __builtin_amdgcn_s_barrier();      // publish: all waves' tile t in LDS
    __builtin_amdgcn_sched_barrier(0); // reads must not hoist above barrier
    bf16x8 ah[2], al[2], bhf[4], blf[4];
#pragma unroll
    for (int mt = 0; mt < 2; ++mt) {
      ah[mt] = *(const bf16x8*)(&Ash[cur][aOff[mt]]);
      al[mt] = *(const bf16x8*)(&Asl[cur][aOff[mt]]);
    }
#pragma unroll
    for (int nt = 0; nt < 4; ++nt) {
      bhf[nt] = *(const bf16x8*)(&Bsh[cur][bOff[nt]]);
      blf[nt] = *(const bf16x8*)(&Bsl[cur][bOff[nt]]);
    }
#pragma unroll
    for (int mt = 0; mt < 2; ++mt)
#pragma unroll
      for (int nt = 0; nt < 4; ++nt) {
        acc[mt][nt] = MFMA16(ah[mt], bhf[nt], acc[mt][nt]);
        acc[mt][nt] = MFMA16(ah[mt], blf[nt], acc[mt][nt]);
        acc[mt][nt] = MFMA16(al[mt], bhf[nt], acc[mt][nt]);
      }
    asm volatile("s_waitcnt lgkmcnt(0)" ::: "memory");  // my reads retired
    __builtin_amdgcn_s_barrier();  // all reads of buf[cur] done -> overwrite ok
  }

  float* Cf = (float*)(g_ws + (z == 0 ? c0o : c1o));
  bf16_t* Ch = (bf16_t*)(g_ws + c0o);
  bf16_t* Cl = (bf16_t*)(g_ws + c1o);
#pragma unroll
  for (int mt = 0; mt < 2; ++mt) {
    const int row0 = m0 + wm * 32 + mt * 16 + quad * 4;
#pragma unroll
    for (int nt = 0; nt < 4; ++nt) {
      const int col = n0 + wn * 64 + nt * 16 + l16;
      float bv = ((EPI >= 2) && z == 0) ? bias[col] : 0.0f;
#pragma unroll
      for (int r = 0; r < 4; ++r) {
        float v = acc[mt][nt][r] + bv;
        if (EPI == 2) v = fmaxf(v, 0.0f);
        long off = (long)(row0 + r) * N + col;
        if (EPI == 0 || EPI == 3) {
          Cf[off] = v;
        } else {
          bf16_t h, l;
          split2(v, h, l);
          Ch[off] = h;
          Cl[off] = l;
        }
      }
    }
  }
}

// ---------------------------------------------------------------------------
// Fused attention (flash-style; reference has NO 1/sqrt(dk) scale).
// grid = (S/64 q-tiles, B*H). block 256 (4 waves); wave owns 16 q rows.
// R15: K staged in LDS (single-buffered, pipelined across iters); V read
// direct-to-register from VT (fragment = 8 contiguous bf16). LDS 41 KiB ->
// 3 blocks/CU. Loop: vmcnt(0); barA; QK+softmax; lgkm(0); barB; stageK(t+1);
// P->Ps->pf; PV (direct V loads, compiler-scheduled waits).
// ---------------------------------------------------------------------------
__global__ __launch_bounds__(256) void attn_kernel(const float* __restrict__ mask) {
  const bf16_t* QKVh = (const bf16_t*)(g_ws + OFF_QKV_HI);
  const bf16_t* QKVl = (const bf16_t*)(g_ws + OFF_QKV_LO);
  const bf16_t* VTh = (const bf16_t*)(g_ws + OFF_VT_HI);
  const bf16_t* VTl = (const bf16_t*)(g_ws + OFF_VT_LO);
  bf16_t* conch = (bf16_t*)(g_ws + OFF_CONC_HI);
  bf16_t* concl = (bf16_t*)(g_ws + OFF_CONC_LO);
  __shared__ __align__(16) bf16_t Ksh[64 * 128];
  __shared__ __align__(16) bf16_t Ksl[64 * 128];
  __shared__ __align__(16) bf16_t Ps[4][16 * 72];  // P hi, +8 pad per row
  const int tid = threadIdx.x;
  const int wave = tid >> 6, lane = tid & 63;
  const int quad = lane >> 4, l16 = lane & 15;
  const int q0 = blockIdx.x * 64;
  const int bh = blockIdx.y, b = bh >> 3, h = bh & 7;

  bf16x8 qfh[4], qfl[4];
  const long qgbase = ((long)(b * 1024) + q0 + wave * 16 + l16) * 3072 + h * 128;
#pragma unroll
  for (int ks = 0; ks < 4; ++ks) {
    qfh[ks] = *(const bf16x8*)(QKVh + qgbase + ks * 32 + quad * 8);
    qfl[ks] = *(const bf16x8*)(QKVl + qgbase + ks * 32 + quad * 8);
  }

  const int sKrow4 = wave * 16 + (lane >> 4);  // + j*4 = actual row
  // per-lane V base: VT[bh][l16][quad*8]; fragment (on,k2,t0) adds
  // on*16*1024 + t0 + k2*32.
  const long vlane = (long)bh * 131072 + (long)l16 * 1024 + quad * 8;

  // K staging: 8 gl2lds per wave
  auto stageK = [&](int tt) {
#pragma unroll
    for (int j = 0; j < 4; ++j) {
      const int r = sKrow4 + j * 4;
      const int c = (lane & 15) ^ ((r & 7) * 2);
      const long kg = ((long)(b * 1024) + tt + r) * 3072 + 1024 + h * 128 + c * 8;
      gl2lds16(QKVh + kg, Ksh + (wave * 16 + j * 4) * 128);
      gl2lds16(QKVl + kg, Ksl + (wave * 16 + j * 4) * 128);
    }
  };

  f32x4 o[8] = {};
  float mi[4] = {-1e30f, -1e30f, -1e30f, -1e30f};
  float li[4] = {0.f, 0.f, 0.f, 0.f};

  stageK(0);  // prologue: K tile 0 in flight (8 loads)

  for (int t0 = 0; t0 < 1024; t0 += 64) {
    asm volatile("s_waitcnt vmcnt(0)" ::: "memory");  // K[t] landed
    __builtin_amdgcn_s_barrier();       // A: K visible to all waves
    __builtin_amdgcn_sched_barrier(0);  // K reads must not hoist above A
    // ---- S = Q @ K^T (split) ----
    f32x4 s4[4] = {};
#pragma unroll
    for (int nt = 0; nt < 4; ++nt) {
      const int krow = nt * 16 + l16;
      const int ksw = (krow & 7) * 2;
#pragma unroll
      for (int ks = 0; ks < 4; ++ks) {
        const int so = krow * 128 + (((ks * 4 + quad) ^ ksw) * 8);
        bf16x8 kfh = *(const bf16x8*)(Ksh + so);
        bf16x8 kfl = *(const bf16x8*)(Ksl + so);
        s4[nt] = MFMA16(qfh[ks], kfh, s4[nt]);
        s4[nt] = MFMA16(qfh[ks], kfl, s4[nt]);
        s4[nt] = MFMA16(qfl[ks], kfh, s4[nt]);
      }
    }
    // mask + online softmax
#pragma unroll
    for (int nt = 0; nt < 4; ++nt) {
      float mv = mask[b * 1024 + t0 + nt * 16 + l16];
      float addv = (1.0f - mv) * (-1e-30f);
#pragma unroll
      for (int r = 0; r < 4; ++r) s4[nt][r] = mv * s4[nt][r] + addv;
    }
#pragma unroll
    for (int r = 0; r < 4; ++r) {
      float mx = fmaxf(fmaxf(s4[0][r], s4[1][r]), fmaxf(s4[2][r], s4[3][r]));
#pragma unroll
      for (int off = 1; off < 16; off <<= 1) mx = fmaxf(mx, __shfl_xor(mx, off, 64));
      float mnew = fmaxf(mi[r], mx);
      float alpha = __expf(mi[r] - mnew);
      float rs = 0.0f;
#pragma unroll
      for (int nt = 0; nt < 4; ++nt) {
        float p = __expf(s4[nt][r] - mnew);
        s4[nt][r] = p;
        rs += p;
      }
#pragma unroll
      for (int off = 1; off < 16; off <<= 1) rs += __shfl_xor(rs, off, 64);
      li[r] = li[r] * alpha + rs;
      mi[r] = mnew;
#pragma unroll
      for (int on = 0; on < 8; ++on) o[on][r] *= alpha;
    }
    asm volatile("s_waitcnt lgkmcnt(0)" ::: "memory");  // my K reads retired
    __builtin_amdgcn_s_barrier();       // B: all waves' K reads done
    __builtin_amdgcn_sched_barrier(0);  // K-stage must not hoist above B
    if (t0 + 64 < 1024) stageK(t0 + 64);  // overwrite K buffer (hidden by PV)
    // P: C-layout -> per-wave LDS -> A-layout (DS in-order per wave)
#pragma unroll
    for (int nt = 0; nt < 4; ++nt)
#pragma unroll
      for (int r = 0; r < 4; ++r)
        Ps[wave][(quad * 4 + r) * 72 + nt * 16 + l16] = (bf16_t)s4[nt][r];
    bf16x8 pf[2];
#pragma unroll
    for (int k2 = 0; k2 < 2; ++k2)
      pf[k2] = *(const bf16x8*)(&Ps[wave][l16 * 72 + k2 * 32 + quad * 8]);
    // ---- O += P @ V (V fragments direct from global VT) ----
#pragma unroll
    for (int k2 = 0; k2 < 2; ++k2) {
#pragma unroll
      for (int on = 0; on < 8; ++on) {
        const long va = vlane + (long)(on * 16) * 1024 + t0 + k2 * 32;
        bf16x8 vfh = *(const bf16x8*)(VTh + va);
        bf16x8 vfl = *(const bf16x8*)(VTl + va);
        o[on] = MFMA16(pf[k2], vfh, o[on]);
        o[on] = MFMA16(pf[k2], vfl, o[on]);
      }
    }
  }
  const int srow_o = q0 + wave * 16 + quad * 4;
#pragma unroll
  for (int r = 0; r < 4; ++r) {
    float inv = 1.0f / li[r];
#pragma unroll
    for (int on = 0; on < 8; ++on) {
      float v = o[on][r] * inv;
      bf16_t hh, ll;
      split2(v, hh, ll);
      long off = (long)(b * 1024 + srow_o + r) * 1024 + h * 128 + on * 16 + l16;
      conch[off] = hh;
      concl[off] = ll;
    }
  }
}

// ---------------------------------------------------------------------------
// Residual + LayerNorm. One block per row (D=1024). Reads X32 + TMP + TMP2
// (split-K partials), writes X32 + split XB; if extf != null (final) writes
// fp32 there instead.
// ---------------------------------------------------------------------------
__global__ __launch_bounds__(256) void ln_kernel(
    const float* __restrict__ gamma, const float* __restrict__ beta, int gidx,
    float* __restrict__ extf) {
  const float* xres = (const float*)(g_ws + OFF_X32);
  const float* y1 = (const float*)(g_ws + OFF_TMP);
  const float* y2 = (const float*)(g_ws + OFF_TMP2);
  float* xout = (float*)(g_ws + OFF_X32);
  bf16_t* xbh = (bf16_t*)(g_ws + OFF_XB_HI);
  bf16_t* xbl = (bf16_t*)(g_ws + OFF_XB_LO);
  const int row = blockIdx.x, tid = threadIdx.x;
  const int wave = tid >> 6, lane = tid & 63;
  const long base = (long)row * 1024 + tid * 4;
  float4 xv = *(const float4*)(xres + base);
  float4 yv = *(const float4*)(y1 + base);
  float4 y2v = *(const float4*)(y2 + base);
  float v0 = xv.x + yv.x + y2v.x, v1 = xv.y + yv.y + y2v.y;
  float v2 = xv.z + yv.z + y2v.z, v3 = xv.w + yv.w + y2v.w;
  float s1 = v0 + v1 + v2 + v3;
  float s2 = v0 * v0 + v1 * v1 + v2 * v2 + v3 * v3;
#pragma unroll
  for (int off = 1; off < 64; off <<= 1) {
    s1 += __shfl_xor(s1, off, 64);
    s2 += __shfl_xor(s2, off, 64);
  }
  __shared__ __align__(16) float r1[4], r2[4];
  if (lane == 0) { r1[wave] = s1; r2[wave] = s2; }
  __syncthreads();
  s1 = r1[0] + r1[1] + r1[2] + r1[3];
  s2 = r2[0] + r2[1] + r2[2] + r2[3];
  const float mean = s1 * (1.0f / 1024.0f);
  float var = s2 * (1.0f / 1024.0f) - mean * mean;
  var = fmaxf(var, 0.0f);
  const float inv = rsqrtf(var + 1e-14f);
  const float g = gamma[gidx], be = beta[gidx];
  float o0 = (v0 - mean) * inv * g + be;
  float o1 = (v1 - mean) * inv * g + be;
  float o2 = (v2 - mean) * inv * g + be;
  float o3 = (v3 - mean) * inv * g + be;
  float4 ov = {o0, o1, o2, o3};
  *(float4*)(xout + base) = ov;
  if (extf) {
    *(float4*)(extf + base) = ov;
  } else {
    bf16_t h0, l0, h1, l1, h2, l2, h3, l3;
    split2(o0, h0, l0); split2(o1, h1, l1);
    split2(o2, h2, l2); split2(o3, h3, l3);
    bf16x4v hv = {h0, h1, h2, h3};
    bf16x4v lv = {l0, l1, l2, l3};
    *(bf16x4v*)(xbh + base) = hv;
    *(bf16x4v*)(xbl + base) = lv;
  }
}

// fp32 input x -> X32 (fp32 copy) + split XB
__global__ __launch_bounds__(256) void cast_f2b(const float* __restrict__ in) {
  float* out = (float*)(g_ws + OFF_X32);
  bf16_t* outh = (bf16_t*)(g_ws + OFF_XB_HI);
  bf16_t* outl = (bf16_t*)(g_ws + OFF_XB_LO);
  long i = ((long)blockIdx.x * 256 + threadIdx.x) * 4;
  float4 v = *(const float4*)(in + i);
  *(float4*)(out + i) = v;
  bf16_t h0, l0, h1, l1, h2, l2, h3, l3;
  split2(v.x, h0, l0); split2(v.y, h1, l1);
  split2(v.z, h2, l2); split2(v.w, h3, l3);
  bf16x4v hv = {h0, h1, h2, h3};
  bf16x4v lv = {l0, l1, l2, l3};
  *(bf16x4v*)(outh + i) = hv;
  *(bf16x4v*)(outl + i) = lv;
}

// tiled transpose+split: out[c*R + r] = split(in[r*C + c]). block (32,8).
__global__ __launch_bounds__(256) void transp_split(
    const float* __restrict__ in, size_t oh_off, size_t ol_off, int R, int C) {
  bf16_t* oh = (bf16_t*)(g_ws + oh_off);
  bf16_t* ol = (bf16_t*)(g_ws + ol_off);
  __shared__ float tile[32][33];
  const int tx = threadIdx.x, ty = threadIdx.y;
  const int c0 = blockIdx.x * 32, r0 = blockIdx.y * 32;
#pragma unroll
  for (int j = 0; j < 4; ++j)
    tile[ty + j * 8][tx] = in[(long)(r0 + ty + j * 8) * C + c0 + tx];
  __syncthreads();
#pragma unroll
  for (int j = 0; j < 4; ++j) {
    float v = tile[tx][ty + j * 8];
    bf16_t h, l;
    split2(v, h, l);
    long off = (long)(c0 + ty + j * 8) * R + r0 + tx;
    oh[off] = h;
    ol[off] = l;
  }
}

// QKV weight repack: Wq/Wk/Wv[h,d,dk] -> WQKV[n = mat*1024 + h*128 + dk][d]
// grid (4, 32, 24): z = mat*8 + h. block (32,8).
__global__ __launch_bounds__(256) void qkvw_trans(
    const float* __restrict__ Wq, const float* __restrict__ Wk,
    const float* __restrict__ Wv) {
  bf16_t* oh = (bf16_t*)(g_ws + OFF_WQKV_HI);
  bf16_t* ol = (bf16_t*)(g_ws + OFF_WQKV_LO);
  __shared__ float tile[32][33];
  const int tx = threadIdx.x, ty = threadIdx.y;
  const int z = blockIdx.z, mat = z >> 3, h = z & 7;
  const float* src = (mat == 0 ? Wq : (mat == 1 ? Wk : Wv)) + h * 131072;
  const int c0 = blockIdx.x * 32, r0 = blockIdx.y * 32;  // c: dk, r: d
#pragma unroll
  for (int j = 0; j < 4; ++j)
    tile[ty + j * 8][tx] = src[(r0 + ty + j * 8) * 128 + c0 + tx];
  __syncthreads();
  const int nbase = mat * 1024 + h * 128;
#pragma unroll
  for (int j = 0; j < 4; ++j) {
    float v = tile[tx][ty + j * 8];
    bf16_t hh, ll;
    split2(v, hh, ll);
    long off = (long)(nbase + c0 + ty + j * 8) * 1024 + r0 + tx;
    oh[off] = hh;
    ol[off] = ll;
  }
}

// V transpose: VT[bh,v,s] = QKV[(b*1024+s)*3072 + 2048 + h*128 + v] (hi & lo)
// grid (32 s-tiles, 4 v-tiles, 32 bh). block (32,8).
__global__ __launch_bounds__(256) void vt_trans() {
  const bf16_t* QKVh = (const bf16_t*)(g_ws + OFF_QKV_HI);
  const bf16_t* QKVl = (const bf16_t*)(g_ws + OFF_QKV_LO);
  bf16_t* VTh = (bf16_t*)(g_ws + OFF_VT_HI);
  bf16_t* VTl = (bf16_t*)(g_ws + OFF_VT_LO);
  __shared__ bf16_t th[32][34];
  __shared__ bf16_t tl[32][34];
  const int tx = threadIdx.x, ty = threadIdx.y;
  const int bh = blockIdx.z, b = bh >> 3, h = bh & 7;
  const int s0 = blockIdx.x * 32, v0 = blockIdx.y * 32;
#pragma unroll
  for (int j = 0; j < 4; ++j) {
    long src = ((long)(b * 1024) + s0 + ty + j * 8) * 3072 + 2048 + h * 128 + v0 + tx;
    th[ty + j * 8][tx] = QKVh[src];
    tl[ty + j * 8][tx] = QKVl[src];
  }
  __syncthreads();
#pragma unroll
  for (int j = 0; j < 4; ++j) {
    long off = (long)bh * 131072 + (long)(v0 + ty + j * 8) * 1024 + s0 + tx;
    VTh[off] = th[tx][ty + j * 8];
    VTl[off] = tl[tx][ty + j * 8];
  }
}

// ---------------------------------------------------------------------------
extern "C" void kernel_launch(void* const* d_in, const int* in_sizes, int n_in,
                              void* d_out, int out_size, void* d_ws, size_t ws_size,
                              hipStream_t stream) {
  const float* x_in = (const float*)d_in[0];
  const float* mask = (const float*)d_in[1];
  const float* Wq = (const float*)d_in[2];
  const float* Wk = (const float*)d_in[3];
  const float* Wv = (const float*)d_in[4];
  const float* Wo = (const float*)d_in[5];
  const float* W1 = (const float*)d_in[6];
  const float* b1 = (const float*)d_in[7];
  const float* W2 = (const float*)d_in[8];
  const float* b2 = (const float*)d_in[9];
  const float* gamma = (const float*)d_in[10];
  const float* beta = (const float*)d_in[11];
  float* out = (float*)d_out;
  (void)d_ws; (void)ws_size; (void)in_sizes; (void)n_in; (void)out_size;

  const dim3 tb(32, 8);
  cast_f2b<<<4096, 256, 0, stream>>>(x_in);

  for (int l = 0; l < 2; ++l) {
    qkvw_trans<<<dim3(4, 32, 24), tb, 0, stream>>>(
        Wq + (long)l * 1048576, Wk + (long)l * 1048576, Wv + (long)l * 1048576);
    transp_split<<<dim3(32, 32), tb, 0, stream>>>(Wo + (long)l * 1048576,
                                                  OFF_WO_HI, OFF_WO_LO, 1024, 1024);
    transp_split<<<dim3(64, 32), tb, 0, stream>>>(W1 + (long)l * 2097152,
                                                  OFF_W1_HI, OFF_W1_LO, 1024, 2048);
    transp_split<<<dim3(32, 64), tb, 0, stream>>>(W2 + (long)l * 2097152,
                                                  OFF_W2_HI, OFF_W2_LO, 2048, 1024);

    // fused QKV GEMM: [4096,1024] @ [3072,1024]^T -> [4096,3072]
    gemm_bt<1><<<dim3(24, 32, 1), 512, 0, stream>>>(
        OFF_XB_HI, OFF_XB_LO, OFF_WQKV_HI, OFF_WQKV_LO,
        OFF_QKV_HI, OFF_QKV_LO, nullptr, 4096, 3072, 1024, 1024);
    vt_trans<<<dim3(32, 4, 32), tb, 0, stream>>>();
    attn_kernel<<<dim3(16, 32), 256, 0, stream>>>(mask);
    // proj: split-K2 -> TMP (z=0) + TMP2 (z=1)
    gemm_bt<0><<<dim3(8, 32, 2), 512, 0, stream>>>(
        OFF_CONC_HI, OFF_CONC_LO, OFF_WO_HI, OFF_WO_LO,
        OFF_TMP, OFF_TMP2, nullptr, 4096, 1024, 1024, 512);
    ln_kernel<<<4096, 256, 0, stream>>>(gamma, beta, 2 * l, nullptr);
    gemm_bt<2><<<dim3(16, 32, 1), 512, 0, stream>>>(
        OFF_XB_HI, OFF_XB_LO, OFF_W1_HI, OFF_W1_LO,
        OFF_H_HI, OFF_H_LO, b1 + l * 2048, 4096, 2048, 1024, 1024);
    // ffn2: split-K2 (K=2048) -> TMP + TMP2; bias on slice 0 only
    gemm_bt<3><<<dim3(8, 32, 2), 512, 0, stream>>>(
        OFF_H_HI, OFF_H_LO, OFF_W2_HI, OFF_W2_LO,
        OFF_TMP, OFF_TMP2, b2 + l * 1024, 4096, 1024, 2048, 1024);
    ln_kernel<<<4096, 256, 0, stream>>>(gamma, beta, 2 * l + 1,
                                        (l == 1) ? out : nullptr);
  }
}

// Round 10
// 791.070 us; speedup vs baseline: 1.2342x; 1.2342x over previous
//
#include <hip/hip_runtime.h>
#include <hip/hip_bf16.h>

// MI355X / gfx950. B=4,S=1024,D=1024,H=8,DK=DV=128,DFF=2048,L=2.
// FP32 in/out. bf16x2-split MFMA (hi*hi + hi*lo + lo*hi) for ~1e-5 relative
// accuracy (unscaled QK^T, score std ~20, sharp softmax).
// Round 16: R9's direct-global-V attn REFUTED (181 µs, MfmaUtil 9.5, FETCH
// 139 MB — per-fragment global loads on the PV critical path). attn reverted
// to R8's proven 3-barrier counted-vmcnt pipeline with V staged in LDS.
// KEEP R9's XCD-chunked gemm_bt swizzle: attn regressed +210 µs but total
// only +164 -> GEMM side likely saved ~45 µs (to be confirmed by counters).
// GEMM core = R6 best: 8-wave 128² tile, dbuf LDS, counted vmcnt(4).
// Split-K2 proj/FFN2 + 3-input LN kept (R3 win).
// Verified MFMA layouts: A[m=lane&15][k=quad*8+j], C/D col=lane&15,row=quad*4+reg.
// Staging swizzle: LDS slot (row, c) holds global chunk c ^ ((row>>1)&3);
// frag read offset = R*32 + ((quad ^ ((R>>1)&3))*8). Bank-conflict-free (proven).

typedef __bf16 bf16_t;
typedef bf16_t bf16x8 __attribute__((ext_vector_type(8)));
typedef bf16_t bf16x4v __attribute__((ext_vector_type(4)));
typedef float f32x4 __attribute__((ext_vector_type(4)));

#define MFMA16(a, b, c) __builtin_amdgcn_mfma_f32_16x16x32_bf16((a), (b), (c), 0, 0, 0)

__device__ __align__(256) unsigned char g_ws[(size_t)192 << 20];

#define MBOFF(x) ((size_t)(x) << 20)
#define OFF_X32 MBOFF(0)        // fp32 running residual (4M floats)
#define OFF_XB_HI MBOFF(16)     // bf16 hi/lo of x (GEMM A input)
#define OFF_XB_LO MBOFF(24)
#define OFF_QKV_HI MBOFF(32)    // fused QKV out [4096][3072]
#define OFF_QKV_LO MBOFF(56)
#define OFF_VT_HI MBOFF(80)     // V transposed [bh,v,s]
#define OFF_VT_LO MBOFF(88)
#define OFF_CONC_HI MBOFF(96)   // attention output [b,s,h*128+v]
#define OFF_CONC_LO MBOFF(104)
#define OFF_TMP MBOFF(112)      // fp32 proj/ffn2 slice-0 output (4M floats)
#define OFF_H_HI MBOFF(128)     // ffn hidden (4096x2048)
#define OFF_H_LO MBOFF(144)
#define OFF_WQKV_HI MBOFF(160)  // [3072][1024]
#define OFF_WQKV_LO MBOFF(166)
#define OFF_WO_HI MBOFF(172)
#define OFF_WO_LO MBOFF(174)
#define OFF_W1_HI MBOFF(176)
#define OFF_W1_LO MBOFF(180)
#define OFF_W2_HI MBOFF(184)
#define OFF_W2_LO MBOFF(188)
// split-K slice-1 fp32 partial. Aliases QKV_HI: QKV is dead from the proj GEMM
// (attn+vt_trans already consumed it) until the next layer's QKV GEMM, which
// runs after ln2 has read TMP2. Stream-ordered, so safe.
#define OFF_TMP2 MBOFF(32)

__device__ __forceinline__ void split2(float v, bf16_t& h, bf16_t& l) {
  h = (bf16_t)v;
  l = (bf16_t)(v - (float)h);
}

// async global->LDS, 16 bytes per lane; LDS dest = wave-uniform base + lane*16
__device__ __forceinline__ void gl2lds16(const bf16_t* g, bf16_t* l) {
  __builtin_amdgcn_global_load_lds(
      (const __attribute__((address_space(1))) unsigned int*)(g),
      (__attribute__((address_space(3))) unsigned int*)(l), 16, 0, 0);
}

// ---------------------------------------------------------------------------
// Split GEMM: C[M,N] = A[M,Ksl] @ Bt[N,Ksl]^T, (hi,lo) bf16 pairs.
// 128x128 tile, BK=32, 512 threads (8 waves). Wave w: m-group (w&3)*32,
// n-group (w>>2)*64. Double-buffered LDS + counted-vmcnt prefetch:
//   iter t: STAGE(nxt, t+1); vmcnt(4); s_barrier; sched_barrier(0);
//           ds_read + 24 MFMA (compiler-interleaved); lgkmcnt(0); s_barrier.
// Per-wave vmcnt audit: steady state has 8 outstanding gl2lds (4 of t, 4 of
// t+1); vmcnt(4) waits exactly t's. End-of-iter lgkmcnt(0)+barrier makes all
// reads of buf[cur] retire before iter t+1 overwrites it. Last iter vmcnt(0).
// XCD-chunked swizzle: hw linear id h (x fastest; XCD = h%8) computes tile
// (h%8)*cpx + h/8, so each XCD works a contiguous tile run (L2 locality).
// Bijective because gridDim.x*gridDim.y % 8 == 0 at every call site.
// Split-K via blockIdx.z: K-range [z*Ksl, (z+1)*Ksl); fp32 epilogues write to
// c0o (z=0) or c1o (z=1); bias applied on z==0 only.
// EPI: 0 = fp32 out, 1 = split out, 2 = split out + bias + relu, 3 = fp32+bias
// ---------------------------------------------------------------------------
template <int EPI>
__global__ __launch_bounds__(512) void gemm_bt(
    size_t a_hi, size_t a_lo, size_t b_hi, size_t b_lo,
    size_t c0o, size_t c1o, const float* __restrict__ bias,
    int M, int N, int Ktot, int Ksl) {
  const bf16_t* Ah = (const bf16_t*)(g_ws + a_hi);
  const bf16_t* Al = (const bf16_t*)(g_ws + a_lo);
  const bf16_t* Bh = (const bf16_t*)(g_ws + b_hi);
  const bf16_t* Bl = (const bf16_t*)(g_ws + b_lo);
  __shared__ __align__(16) bf16_t Ash[2][128 * 32];
  __shared__ __align__(16) bf16_t Asl[2][128 * 32];
  __shared__ __align__(16) bf16_t Bsh[2][128 * 32];
  __shared__ __align__(16) bf16_t Bsl[2][128 * 32];
  const int tid = threadIdx.x;
  const int wave = tid >> 6, lane = tid & 63;
  const int quad = lane >> 4, l16 = lane & 15;
  const int wm = wave & 3, wn = wave >> 2;
  // XCD-chunked tile swizzle (see header)
  const int gx = gridDim.x;
  int lid = blockIdx.y * gx + blockIdx.x;
  const int cpx = (gx * gridDim.y) >> 3;
  lid = (lid & 7) * cpx + (lid >> 3);
  const int m0 = (lid / gx) * 128, n0 = (lid % gx) * 128;
  const int z = blockIdx.z;
  // staging: wave covers rows wave*16..+15, lane -> (row lane>>2, chunk lane&3)
  const int srow = wave * 16 + (lane >> 2);
  const int scp = (lane & 3) ^ ((srow >> 1) & 3);
  const long agoff = (long)(m0 + srow) * Ktot + (long)z * Ksl + scp * 8;
  const long bgoff = (long)(n0 + srow) * Ktot + (long)z * Ksl + scp * 8;
  const int ldsw = wave * 512;  // wave's 16 rows * 32 elems
  // frag read offsets (swizzled)
  int aOff[2], bOff[4];
#pragma unroll
  for (int mt = 0; mt < 2; ++mt) {
    int R = wm * 32 + mt * 16 + l16;
    aOff[mt] = R * 32 + ((quad ^ ((R >> 1) & 3)) * 8);
  }
#pragma unroll
  for (int nt = 0; nt < 4; ++nt) {
    int R = wn * 64 + nt * 16 + l16;
    bOff[nt] = R * 32 + ((quad ^ ((R >> 1) & 3)) * 8);
  }
  f32x4 acc[2][4] = {};
  const int nk = Ksl >> 5;

  // prologue: stage tile 0 into buffer 0 (4 gl2lds per wave)
  gl2lds16(Ah + agoff, &Ash[0][ldsw]);
  gl2lds16(Al + agoff, &Asl[0][ldsw]);
  gl2lds16(Bh + bgoff, &Bsh[0][ldsw]);
  gl2lds16(Bl + bgoff, &Bsl[0][ldsw]);

  for (int t = 0; t < nk; ++t) {
    const int cur = t & 1, nxt = cur ^ 1;
    const long ko = (long)(t + 1) * 32;
    if (t + 1 < nk) {
      gl2lds16(Ah + agoff + ko, &Ash[nxt][ldsw]);
      gl2lds16(Al + agoff + ko, &Asl[nxt][ldsw]);
      gl2lds16(Bh + bgoff + ko, &Bsh[nxt][ldsw]);
      gl2lds16(Bl + bgoff + ko, &Bsl[nxt][ldsw]);
      asm volatile("s_waitcnt vmcnt(4)" ::: "memory");  // tile t landed
    } else {
      asm volatile("s_waitcnt vmcnt(0)" ::: "memory");
    }
    __builtin_amdgcn_s_barrier();      // publish: all waves' tile t in LDS
    __builtin_amdgcn_sched_barrier(0); // reads must not hoist above barrier
    bf16x8 ah[2], al[2], bhf[4], blf[4];
#pragma unroll
    for (int mt = 0; mt < 2; ++mt) {
      ah[mt] = *(const bf16x8*)(&Ash[cur][aOff[mt]]);
      al[mt] = *(const bf16x8*)(&Asl[cur][aOff[mt]]);
    }
#pragma unroll
    for (int nt = 0; nt < 4; ++nt) {
      bhf[nt] = *(const bf16x8*)(&Bsh[cur][bOff[nt]]);
      blf[nt] = *(const bf16x8*)(&Bsl[cur][bOff[nt]]);
    }
#pragma unroll
    for (int mt = 0; mt < 2; ++mt)
#pragma unroll
      for (int nt = 0; nt < 4; ++nt) {
        acc[mt][nt] = MFMA16(ah[mt], bhf[nt], acc[mt][nt]);
        acc[mt][nt] = MFMA16(ah[mt], blf[nt], acc[mt][nt]);
        acc[mt][nt] = MFMA16(al[mt], bhf[nt], acc[mt][nt]);
      }
    asm volatile("s_waitcnt lgkmcnt(0)" ::: "memory");  // my reads retired
    __builtin_amdgcn_s_barrier();  // all reads of buf[cur] done -> overwrite ok
  }

  float* Cf = (float*)(g_ws + (z == 0 ? c0o : c1o));
  bf16_t* Ch = (bf16_t*)(g_ws + c0o);
  bf16_t* Cl = (bf16_t*)(g_ws + c1o);
#pragma unroll
  for (int mt = 0; mt < 2; ++mt) {
    const int row0 = m0 + wm * 32 + mt * 16 + quad * 4;
#pragma unroll
    for (int nt = 0; nt < 4; ++nt) {
      const int col = n0 + wn * 64 + nt * 16 + l16;
      float bv = ((EPI >= 2) && z == 0) ? bias[col] : 0.0f;
#pragma unroll
      for (int r = 0; r < 4; ++r) {
        float v = acc[mt][nt][r] + bv;
        if (EPI == 2) v = fmaxf(v, 0.0f);
        long off = (long)(row0 + r) * N + col;
        if (EPI == 0 || EPI == 3) {
          Cf[off] = v;
        } else {
          bf16_t h, l;
          split2(v, h, l);
          Ch[off] = h;
          Cl[off] = l;
        }
      }
    }
  }
}

// ---------------------------------------------------------------------------
// Fused attention (flash-style; reference has NO 1/sqrt(dk) scale).
// grid = (S/64 q-tiles, B*H). block 256 (4 waves); wave owns 16 q rows.
// R8 pipeline (proven): stage V; vmcnt(8) [K only]; barA; QK+softmax (V in
// flight); vmcnt(0); barB; stage next K into dead K buf; PV; lgkm(0); barC.
// ---------------------------------------------------------------------------
__global__ __launch_bounds__(256) void attn_kernel(const float* __restrict__ mask) {
  const bf16_t* QKVh = (const bf16_t*)(g_ws + OFF_QKV_HI);
  const bf16_t* QKVl = (const bf16_t*)(g_ws + OFF_QKV_LO);
  const bf16_t* VTh = (const bf16_t*)(g_ws + OFF_VT_HI);
  const bf16_t* VTl = (const bf16_t*)(g_ws + OFF_VT_LO);
  bf16_t* conch = (bf16_t*)(g_ws + OFF_CONC_HI);
  bf16_t* concl = (bf16_t*)(g_ws + OFF_CONC_LO);
  __shared__ __align__(16) bf16_t Ksh[64 * 128];
  __shared__ __align__(16) bf16_t Ksl[64 * 128];
  __shared__ __align__(16) bf16_t Vsh[128 * 64];
  __shared__ __align__(16) bf16_t Vsl[128 * 64];
  __shared__ __align__(16) bf16_t Ps[4][16 * 72];  // P hi, +8 pad per row
  const int tid = threadIdx.x;
  const int wave = tid >> 6, lane = tid & 63;
  const int quad = lane >> 4, l16 = lane & 15;
  const int q0 = blockIdx.x * 64;
  const int bh = blockIdx.y, b = bh >> 3, h = bh & 7;

  bf16x8 qfh[4], qfl[4];
  const long qgbase = ((long)(b * 1024) + q0 + wave * 16 + l16) * 3072 + h * 128;
#pragma unroll
  for (int ks = 0; ks < 4; ++ks) {
    qfh[ks] = *(const bf16x8*)(QKVh + qgbase + ks * 32 + quad * 8);
    qfl[ks] = *(const bf16x8*)(QKVl + qgbase + ks * 32 + quad * 8);
  }

  const int sKrow4 = wave * 16 + (lane >> 4);  // + j*4 = actual row
  const int sVrow = wave * 32 + (lane >> 3);   // + j*8 (row&7 invariant)
  const int sVc = (lane & 7) ^ (sVrow & 7);
  const long vgbase = (long)bh * 131072 + (long)sVrow * 1024 + sVc * 8;

  // staging helpers: 8 gl2lds each per wave
  auto stageK = [&](int tt) {
#pragma unroll
    for (int j = 0; j < 4; ++j) {
      const int r = sKrow4 + j * 4;
      const int c = (lane & 15) ^ ((r & 7) * 2);
      const long kg = ((long)(b * 1024) + tt + r) * 3072 + 1024 + h * 128 + c * 8;
      gl2lds16(QKVh + kg, Ksh + (wave * 16 + j * 4) * 128);
      gl2lds16(QKVl + kg, Ksl + (wave * 16 + j * 4) * 128);
    }
  };
  auto stageV = [&](int tt) {
#pragma unroll
    for (int j = 0; j < 4; ++j) {
      const long vg = vgbase + (long)(j * 8) * 1024 + tt;
      gl2lds16(VTh + vg, Vsh + (wave * 32 + j * 8) * 64);
      gl2lds16(VTl + vg, Vsl + (wave * 32 + j * 8) * 64);
    }
  };

  f32x4 o[8] = {};
  float mi[4] = {-1e30f, -1e30f, -1e30f, -1e30f};
  float li[4] = {0.f, 0.f, 0.f, 0.f};

  stageK(0);  // prologue: K tile 0 in flight (8 loads)

  for (int t0 = 0; t0 < 1024; t0 += 64) {
    stageV(t0);  // V tile in flight (8 loads; K's 8 older)
    asm volatile("s_waitcnt vmcnt(8)" ::: "memory");  // K[t] landed; V flying
    __builtin_amdgcn_s_barrier();       // A: K visible to all waves
    __builtin_amdgcn_sched_barrier(0);  // K reads must not hoist above A
    // ---- S = Q @ K^T (split) ----
    f32x4 s4[4] = {};
#pragma unroll
    for (int nt = 0; nt < 4; ++nt) {
      const int krow = nt * 16 + l16;
      const int ksw = (krow & 7) * 2;
#pragma unroll
      for (int ks = 0; ks < 4; ++ks) {
        const int so = krow * 128 + (((ks * 4 + quad) ^ ksw) * 8);
        bf16x8 kfh = *(const bf16x8*)(Ksh + so);
        bf16x8 kfl = *(const bf16x8*)(Ksl + so);
        s4[nt] = MFMA16(qfh[ks], kfh, s4[nt]);
        s4[nt] = MFMA16(qfh[ks], kfl, s4[nt]);
        s4[nt] = MFMA16(qfl[ks], kfh, s4[nt]);
      }
    }
    // mask + online softmax (V loads still in flight underneath)
#pragma unroll
    for (int nt = 0; nt < 4; ++nt) {
      float mv = mask[b * 1024 + t0 + nt * 16 + l16];
      float addv = (1.0f - mv) * (-1e-30f);
#pragma unroll
      for (int r = 0; r < 4; ++r) s4[nt][r] = mv * s4[nt][r] + addv;
    }
#pragma unroll
    for (int r = 0; r < 4; ++r) {
      float mx = fmaxf(fmaxf(s4[0][r], s4[1][r]), fmaxf(s4[2][r], s4[3][r]));
#pragma unroll
      for (int off = 1; off < 16; off <<= 1) mx = fmaxf(mx, __shfl_xor(mx, off, 64));
      float mnew = fmaxf(mi[r], mx);
      float alpha = __expf(mi[r] - mnew);
      float rs = 0.0f;
#pragma unroll
      for (int nt = 0; nt < 4; ++nt) {
        float p = __expf(s4[nt][r] - mnew);
        s4[nt][r] = p;
        rs += p;
      }
#pragma unroll
      for (int off = 1; off < 16; off <<= 1) rs += __shfl_xor(rs, off, 64);
      li[r] = li[r] * alpha + rs;
      mi[r] = mnew;
#pragma unroll
      for (int on = 0; on < 8; ++on) o[on][r] *= alpha;
    }
    asm volatile("s_waitcnt vmcnt(0)" ::: "memory");  // V[t] (+mask) landed
    __builtin_amdgcn_s_barrier();       // B: V visible; all K reads retired
    __builtin_amdgcn_sched_barrier(0);  // V reads / K-stage must not hoist
    if (t0 + 64 < 1024) stageK(t0 + 64);  // overwrite dead K buffer
    // P: C-layout -> per-wave LDS -> A-layout (DS in-order per wave)
#pragma unroll
    for (int nt = 0; nt < 4; ++nt)
#pragma unroll
      for (int r = 0; r < 4; ++r)
        Ps[wave][(quad * 4 + r) * 72 + nt * 16 + l16] = (bf16_t)s4[nt][r];
    bf16x8 pf[2];
#pragma unroll
    for (int k2 = 0; k2 < 2; ++k2)
      pf[k2] = *(const bf16x8*)(&Ps[wave][l16 * 72 + k2 * 32 + quad * 8]);
    // ---- O += P @ V ----
#pragma unroll
    for (int k2 = 0; k2 < 2; ++k2) {
#pragma unroll
      for (int on = 0; on < 8; ++on) {
        const int vrow = on * 16 + l16;
        const int so = vrow * 64 + (((k2 * 4 + quad) ^ (vrow & 7)) * 8);
        bf16x8 vfh = *(const bf16x8*)(Vsh + so);
        bf16x8 vfl = *(const bf16x8*)(Vsl + so);
        o[on] = MFMA16(pf[k2], vfh, o[on]);
        o[on] = MFMA16(pf[k2], vfl, o[on]);
      }
    }
    asm volatile("s_waitcnt lgkmcnt(0)" ::: "memory");  // my V/P reads retired
    __builtin_amdgcn_s_barrier();       // C: V buffer free for next tile
    __builtin_amdgcn_sched_barrier(0);  // next stageV must not hoist above C
  }
  const int srow_o = q0 + wave * 16 + quad * 4;
#pragma unroll
  for (int r = 0; r < 4; ++r) {
    float inv = 1.0f / li[r];
#pragma unroll
    for (int on = 0; on < 8; ++on) {
      float v = o[on][r] * inv;
      bf16_t hh, ll;
      split2(v, hh, ll);
      long off = (long)(b * 1024 + srow_o + r) * 1024 + h * 128 + on * 16 + l16;
      conch[off] = hh;
      concl[off] = ll;
    }
  }
}

// ---------------------------------------------------------------------------
// Residual + LayerNorm. One block per row (D=1024). Reads X32 + TMP + TMP2
// (split-K partials), writes X32 + split XB; if extf != null (final) writes
// fp32 there instead.
// ---------------------------------------------------------------------------
__global__ __launch_bounds__(256) void ln_kernel(
    const float* __restrict__ gamma, const float* __restrict__ beta, int gidx,
    float* __restrict__ extf) {
  const float* xres = (const float*)(g_ws + OFF_X32);
  const float* y1 = (const float*)(g_ws + OFF_TMP);
  const float* y2 = (const float*)(g_ws + OFF_TMP2);
  float* xout = (float*)(g_ws + OFF_X32);
  bf16_t* xbh = (bf16_t*)(g_ws + OFF_XB_HI);
  bf16_t* xbl = (bf16_t*)(g_ws + OFF_XB_LO);
  const int row = blockIdx.x, tid = threadIdx.x;
  const int wave = tid >> 6, lane = tid & 63;
  const long base = (long)row * 1024 + tid * 4;
  float4 xv = *(const float4*)(xres + base);
  float4 yv = *(const float4*)(y1 + base);
  float4 y2v = *(const float4*)(y2 + base);
  float v0 = xv.x + yv.x + y2v.x, v1 = xv.y + yv.y + y2v.y;
  float v2 = xv.z + yv.z + y2v.z, v3 = xv.w + yv.w + y2v.w;
  float s1 = v0 + v1 + v2 + v3;
  float s2 = v0 * v0 + v1 * v1 + v2 * v2 + v3 * v3;
#pragma unroll
  for (int off = 1; off < 64; off <<= 1) {
    s1 += __shfl_xor(s1, off, 64);
    s2 += __shfl_xor(s2, off, 64);
  }
  __shared__ __align__(16) float r1[4], r2[4];
  if (lane == 0) { r1[wave] = s1; r2[wave] = s2; }
  __syncthreads();
  s1 = r1[0] + r1[1] + r1[2] + r1[3];
  s2 = r2[0] + r2[1] + r2[2] + r2[3];
  const float mean = s1 * (1.0f / 1024.0f);
  float var = s2 * (1.0f / 1024.0f) - mean * mean;
  var = fmaxf(var, 0.0f);
  const float inv = rsqrtf(var + 1e-14f);
  const float g = gamma[gidx], be = beta[gidx];
  float o0 = (v0 - mean) * inv * g + be;
  float o1 = (v1 - mean) * inv * g + be;
  float o2 = (v2 - mean) * inv * g + be;
  float o3 = (v3 - mean) * inv * g + be;
  float4 ov = {o0, o1, o2, o3};
  *(float4*)(xout + base) = ov;
  if (extf) {
    *(float4*)(extf + base) = ov;
  } else {
    bf16_t h0, l0, h1, l1, h2, l2, h3, l3;
    split2(o0, h0, l0); split2(o1, h1, l1);
    split2(o2, h2, l2); split2(o3, h3, l3);
    bf16x4v hv = {h0, h1, h2, h3};
    bf16x4v lv = {l0, l1, l2, l3};
    *(bf16x4v*)(xbh + base) = hv;
    *(bf16x4v*)(xbl + base) = lv;
  }
}

// fp32 input x -> X32 (fp32 copy) + split XB
__global__ __launch_bounds__(256) void cast_f2b(const float* __restrict__ in) {
  float* out = (float*)(g_ws + OFF_X32);
  bf16_t* outh = (bf16_t*)(g_ws + OFF_XB_HI);
  bf16_t* outl = (bf16_t*)(g_ws + OFF_XB_LO);
  long i = ((long)blockIdx.x * 256 + threadIdx.x) * 4;
  float4 v = *(const float4*)(in + i);
  *(float4*)(out + i) = v;
  bf16_t h0, l0, h1, l1, h2, l2, h3, l3;
  split2(v.x, h0, l0); split2(v.y, h1, l1);
  split2(v.z, h2, l2); split2(v.w, h3, l3);
  bf16x4v hv = {h0, h1, h2, h3};
  bf16x4v lv = {l0, l1, l2, l3};
  *(bf16x4v*)(outh + i) = hv;
  *(bf16x4v*)(outl + i) = lv;
}

// tiled transpose+split: out[c*R + r] = split(in[r*C + c]). block (32,8).
__global__ __launch_bounds__(256) void transp_split(
    const float* __restrict__ in, size_t oh_off, size_t ol_off, int R, int C) {
  bf16_t* oh = (bf16_t*)(g_ws + oh_off);
  bf16_t* ol = (bf16_t*)(g_ws + ol_off);
  __shared__ float tile[32][33];
  const int tx = threadIdx.x, ty = threadIdx.y;
  const int c0 = blockIdx.x * 32, r0 = blockIdx.y * 32;
#pragma unroll
  for (int j = 0; j < 4; ++j)
    tile[ty + j * 8][tx] = in[(long)(r0 + ty + j * 8) * C + c0 + tx];
  __syncthreads();
#pragma unroll
  for (int j = 0; j < 4; ++j) {
    float v = tile[tx][ty + j * 8];
    bf16_t h, l;
    split2(v, h, l);
    long off = (long)(c0 + ty + j * 8) * R + r0 + tx;
    oh[off] = h;
    ol[off] = l;
  }
}

// QKV weight repack: Wq/Wk/Wv[h,d,dk] -> WQKV[n = mat*1024 + h*128 + dk][d]
// grid (4, 32, 24): z = mat*8 + h. block (32,8).
__global__ __launch_bounds__(256) void qkvw_trans(
    const float* __restrict__ Wq, const float* __restrict__ Wk,
    const float* __restrict__ Wv) {
  bf16_t* oh = (bf16_t*)(g_ws + OFF_WQKV_HI);
  bf16_t* ol = (bf16_t*)(g_ws + OFF_WQKV_LO);
  __shared__ float tile[32][33];
  const int tx = threadIdx.x, ty = threadIdx.y;
  const int z = blockIdx.z, mat = z >> 3, h = z & 7;
  const float* src = (mat == 0 ? Wq : (mat == 1 ? Wk : Wv)) + h * 131072;
  const int c0 = blockIdx.x * 32, r0 = blockIdx.y * 32;  // c: dk, r: d
#pragma unroll
  for (int j = 0; j < 4; ++j)
    tile[ty + j * 8][tx] = src[(r0 + ty + j * 8) * 128 + c0 + tx];
  __syncthreads();
  const int nbase = mat * 1024 + h * 128;
#pragma unroll
  for (int j = 0; j < 4; ++j) {
    float v = tile[tx][ty + j * 8];
    bf16_t hh, ll;
    split2(v, hh, ll);
    long off = (long)(nbase + c0 + ty + j * 8) * 1024 + r0 + tx;
    oh[off] = hh;
    ol[off] = ll;
  }
}

// V transpose: VT[bh,v,s] = QKV[(b*1024+s)*3072 + 2048 + h*128 + v] (hi & lo)
// grid (32 s-tiles, 4 v-tiles, 32 bh). block (32,8).
__global__ __launch_bounds__(256) void vt_trans() {
  const bf16_t* QKVh = (const bf16_t*)(g_ws + OFF_QKV_HI);
  const bf16_t* QKVl = (const bf16_t*)(g_ws + OFF_QKV_LO);
  bf16_t* VTh = (bf16_t*)(g_ws + OFF_VT_HI);
  bf16_t* VTl = (bf16_t*)(g_ws + OFF_VT_LO);
  __shared__ bf16_t th[32][34];
  __shared__ bf16_t tl[32][34];
  const int tx = threadIdx.x, ty = threadIdx.y;
  const int bh = blockIdx.z, b = bh >> 3, h = bh & 7;
  const int s0 = blockIdx.x * 32, v0 = blockIdx.y * 32;
#pragma unroll
  for (int j = 0; j < 4; ++j) {
    long src = ((long)(b * 1024) + s0 + ty + j * 8) * 3072 + 2048 + h * 128 + v0 + tx;
    th[ty + j * 8][tx] = QKVh[src];
    tl[ty + j * 8][tx] = QKVl[src];
  }
  __syncthreads();
#pragma unroll
  for (int j = 0; j < 4; ++j) {
    long off = (long)bh * 131072 + (long)(v0 + ty + j * 8) * 1024 + s0 + tx;
    VTh[off] = th[tx][ty + j * 8];
    VTl[off] = tl[tx][ty + j * 8];
  }
}

// ---------------------------------------------------------------------------
extern "C" void kernel_launch(void* const* d_in, const int* in_sizes, int n_in,
                              void* d_out, int out_size, void* d_ws, size_t ws_size,
                              hipStream_t stream) {
  const float* x_in = (const float*)d_in[0];
  const float* mask = (const float*)d_in[1];
  const float* Wq = (const float*)d_in[2];
  const float* Wk = (const float*)d_in[3];
  const float* Wv = (const float*)d_in[4];
  const float* Wo = (const float*)d_in[5];
  const float* W1 = (const float*)d_in[6];
  const float* b1 = (const float*)d_in[7];
  const float* W2 = (const float*)d_in[8];
  const float* b2 = (const float*)d_in[9];
  const float* gamma = (const float*)d_in[10];
  const float* beta = (const float*)d_in[11];
  float* out = (float*)d_out;
  (void)d_ws; (void)ws_size; (void)in_sizes; (void)n_in; (void)out_size;

  const dim3 tb(32, 8);
  cast_f2b<<<4096, 256, 0, stream>>>(x_in);

  for (int l = 0; l < 2; ++l) {
    qkvw_trans<<<dim3(4, 32, 24), tb, 0, stream>>>(
        Wq + (long)l * 1048576, Wk + (long)l * 1048576, Wv + (long)l * 1048576);
    transp_split<<<dim3(32, 32), tb, 0, stream>>>(Wo + (long)l * 1048576,
                                                  OFF_WO_HI, OFF_WO_LO, 1024, 1024);
    transp_split<<<dim3(64, 32), tb, 0, stream>>>(W1 + (long)l * 2097152,
                                                  OFF_W1_HI, OFF_W1_LO, 1024, 2048);
    transp_split<<<dim3(32, 64), tb, 0, stream>>>(W2 + (long)l * 2097152,
                                                  OFF_W2_HI, OFF_W2_LO, 2048, 1024);

    // fused QKV GEMM: [4096,1024] @ [3072,1024]^T -> [4096,3072]
    gemm_bt<1><<<dim3(24, 32, 1), 512, 0, stream>>>(
        OFF_XB_HI, OFF_XB_LO, OFF_WQKV_HI, OFF_WQKV_LO,
        OFF_QKV_HI, OFF_QKV_LO, nullptr, 4096, 3072, 1024, 1024);
    vt_trans<<<dim3(32, 4, 32), tb, 0, stream>>>();
    attn_kernel<<<dim3(16, 32), 256, 0, stream>>>(mask);
    // proj: split-K2 -> TMP (z=0) + TMP2 (z=1)
    gemm_bt<0><<<dim3(8, 32, 2), 512, 0, stream>>>(
        OFF_CONC_HI, OFF_CONC_LO, OFF_WO_HI, OFF_WO_LO,
        OFF_TMP, OFF_TMP2, nullptr, 4096, 1024, 1024, 512);
    ln_kernel<<<4096, 256, 0, stream>>>(gamma, beta, 2 * l, nullptr);
    gemm_bt<2><<<dim3(16, 32, 1), 512, 0, stream>>>(
        OFF_XB_HI, OFF_XB_LO, OFF_W1_HI, OFF_W1_LO,
        OFF_H_HI, OFF_H_LO, b1 + l * 2048, 4096, 2048, 1024, 1024);
    // ffn2: split-K2 (K=2048) -> TMP + TMP2; bias on slice 0 only
    gemm_bt<3><<<dim3(8, 32, 2), 512, 0, stream>>>(
        OFF_H_HI, OFF_H_LO, OFF_W2_HI, OFF_W2_LO,
        OFF_TMP, OFF_TMP2, b2 + l * 1024, 4096, 1024, 2048, 1024);
    ln_kernel<<<4096, 256, 0, stream>>>(gamma, beta, 2 * l + 1,
                                        (l == 1) ? out : nullptr);
  }
}

// Round 11
// 775.224 us; speedup vs baseline: 1.2594x; 1.0204x over previous
//
#include <hip/hip_runtime.h>
#include <hip/hip_bf16.h>

// MI355X / gfx950. B=4,S=1024,D=1024,H=8,DK=DV=128,DFF=2048,L=2.
// FP32 in/out. bf16x2-split MFMA (hi*hi + hi*lo + lo*hi) for ~1e-5 relative
// accuracy (unscaled QK^T, score std ~20, sharp softmax).
// Round 17: vt_trans ELIMINATED — QKV GEMM epilogue (EPI=4) writes the V
// third (cols>=2048) directly transposed into VT[bh][v][s]: each thread's 4
// r-values are 4 consecutive s -> one contiguous bf16x4 (8B) store at
// ((b*8+h)<<17)+(v<<10)+s0. Q,K (cols<2048) keep the normal split layout
// (attn reads Q,K from QKV, V only from VT). Branch is block-uniform
// (2048 % 128 == 0). Saves 2 x ~64MB vt_trans traffic + 2 launches.
// R10 base kept verbatim otherwise: XCD-chunked gemm swizzle (measured-best
// config), R8 attn 3-barrier counted-vmcnt pipeline, R6 GEMM core (8-wave
// 128² dbuf + vmcnt(4)), split-K2 proj/FFN2 + 3-input LN.
// Verified MFMA layouts: A[m=lane&15][k=quad*8+j], C/D col=lane&15,row=quad*4+reg.
// Staging swizzle: LDS slot (row, c) holds global chunk c ^ ((row>>1)&3);
// frag read offset = R*32 + ((quad ^ ((R>>1)&3))*8). Bank-conflict-free (proven).

typedef __bf16 bf16_t;
typedef bf16_t bf16x8 __attribute__((ext_vector_type(8)));
typedef bf16_t bf16x4v __attribute__((ext_vector_type(4)));
typedef float f32x4 __attribute__((ext_vector_type(4)));

#define MFMA16(a, b, c) __builtin_amdgcn_mfma_f32_16x16x32_bf16((a), (b), (c), 0, 0, 0)

__device__ __align__(256) unsigned char g_ws[(size_t)192 << 20];

#define MBOFF(x) ((size_t)(x) << 20)
#define OFF_X32 MBOFF(0)        // fp32 running residual (4M floats)
#define OFF_XB_HI MBOFF(16)     // bf16 hi/lo of x (GEMM A input)
#define OFF_XB_LO MBOFF(24)
#define OFF_QKV_HI MBOFF(32)    // fused QKV out [4096][3072] (Q,K cols only)
#define OFF_QKV_LO MBOFF(56)
#define OFF_VT_HI MBOFF(80)     // V transposed [bh,v,s]
#define OFF_VT_LO MBOFF(88)
#define OFF_CONC_HI MBOFF(96)   // attention output [b,s,h*128+v]
#define OFF_CONC_LO MBOFF(104)
#define OFF_TMP MBOFF(112)      // fp32 proj/ffn2 slice-0 output (4M floats)
#define OFF_H_HI MBOFF(128)     // ffn hidden (4096x2048)
#define OFF_H_LO MBOFF(144)
#define OFF_WQKV_HI MBOFF(160)  // [3072][1024]
#define OFF_WQKV_LO MBOFF(166)
#define OFF_WO_HI MBOFF(172)
#define OFF_WO_LO MBOFF(174)
#define OFF_W1_HI MBOFF(176)
#define OFF_W1_LO MBOFF(180)
#define OFF_W2_HI MBOFF(184)
#define OFF_W2_LO MBOFF(188)
// split-K slice-1 fp32 partial. Aliases QKV_HI: QKV's Q,K part is dead from
// the proj GEMM until the next layer's QKV GEMM (which runs after ln2 read
// TMP2); the V-third of QKV is never read at all (V lives in VT only).
#define OFF_TMP2 MBOFF(32)

__device__ __forceinline__ void split2(float v, bf16_t& h, bf16_t& l) {
  h = (bf16_t)v;
  l = (bf16_t)(v - (float)h);
}

// async global->LDS, 16 bytes per lane; LDS dest = wave-uniform base + lane*16
__device__ __forceinline__ void gl2lds16(const bf16_t* g, bf16_t* l) {
  __builtin_amdgcn_global_load_lds(
      (const __attribute__((address_space(1))) unsigned int*)(g),
      (__attribute__((address_space(3))) unsigned int*)(l), 16, 0, 0);
}

// ---------------------------------------------------------------------------
// Split GEMM: C[M,N] = A[M,Ksl] @ Bt[N,Ksl]^T, (hi,lo) bf16 pairs.
// 128x128 tile, BK=32, 512 threads (8 waves). Double-buffered LDS +
// counted-vmcnt prefetch (R6 core; see earlier round headers for the audit).
// XCD-chunked swizzle (bijective: gx*gy % 8 == 0 at all call sites).
// EPI: 0 = fp32 out (z picks c0/c1), 1 = split out, 2 = split+bias+relu,
//      3 = fp32+bias (z==0 only), 4 = QKV: split out, V-cols -> VT transposed.
// ---------------------------------------------------------------------------
template <int EPI>
__global__ __launch_bounds__(512) void gemm_bt(
    size_t a_hi, size_t a_lo, size_t b_hi, size_t b_lo,
    size_t c0o, size_t c1o, const float* __restrict__ bias,
    int M, int N, int Ktot, int Ksl) {
  const bf16_t* Ah = (const bf16_t*)(g_ws + a_hi);
  const bf16_t* Al = (const bf16_t*)(g_ws + a_lo);
  const bf16_t* Bh = (const bf16_t*)(g_ws + b_hi);
  const bf16_t* Bl = (const bf16_t*)(g_ws + b_lo);
  __shared__ __align__(16) bf16_t Ash[2][128 * 32];
  __shared__ __align__(16) bf16_t Asl[2][128 * 32];
  __shared__ __align__(16) bf16_t Bsh[2][128 * 32];
  __shared__ __align__(16) bf16_t Bsl[2][128 * 32];
  const int tid = threadIdx.x;
  const int wave = tid >> 6, lane = tid & 63;
  const int quad = lane >> 4, l16 = lane & 15;
  const int wm = wave & 3, wn = wave >> 2;
  // XCD-chunked tile swizzle
  const int gx = gridDim.x;
  int lid = blockIdx.y * gx + blockIdx.x;
  const int cpx = (gx * gridDim.y) >> 3;
  lid = (lid & 7) * cpx + (lid >> 3);
  const int m0 = (lid / gx) * 128, n0 = (lid % gx) * 128;
  const int z = blockIdx.z;
  // staging: wave covers rows wave*16..+15, lane -> (row lane>>2, chunk lane&3)
  const int srow = wave * 16 + (lane >> 2);
  const int scp = (lane & 3) ^ ((srow >> 1) & 3);
  const long agoff = (long)(m0 + srow) * Ktot + (long)z * Ksl + scp * 8;
  const long bgoff = (long)(n0 + srow) * Ktot + (long)z * Ksl + scp * 8;
  const int ldsw = wave * 512;  // wave's 16 rows * 32 elems
  // frag read offsets (swizzled)
  int aOff[2], bOff[4];
#pragma unroll
  for (int mt = 0; mt < 2; ++mt) {
    int R = wm * 32 + mt * 16 + l16;
    aOff[mt] = R * 32 + ((quad ^ ((R >> 1) & 3)) * 8);
  }
#pragma unroll
  for (int nt = 0; nt < 4; ++nt) {
    int R = wn * 64 + nt * 16 + l16;
    bOff[nt] = R * 32 + ((quad ^ ((R >> 1) & 3)) * 8);
  }
  f32x4 acc[2][4] = {};
  const int nk = Ksl >> 5;

  // prologue: stage tile 0 into buffer 0 (4 gl2lds per wave)
  gl2lds16(Ah + agoff, &Ash[0][ldsw]);
  gl2lds16(Al + agoff, &Asl[0][ldsw]);
  gl2lds16(Bh + bgoff, &Bsh[0][ldsw]);
  gl2lds16(Bl + bgoff, &Bsl[0][ldsw]);

  for (int t = 0; t < nk; ++t) {
    const int cur = t & 1, nxt = cur ^ 1;
    const long ko = (long)(t + 1) * 32;
    if (t + 1 < nk) {
      gl2lds16(Ah + agoff + ko, &Ash[nxt][ldsw]);
      gl2lds16(Al + agoff + ko, &Asl[nxt][ldsw]);
      gl2lds16(Bh + bgoff + ko, &Bsh[nxt][ldsw]);
      gl2lds16(Bl + bgoff + ko, &Bsl[nxt][ldsw]);
      asm volatile("s_waitcnt vmcnt(4)" ::: "memory");  // tile t landed
    } else {
      asm volatile("s_waitcnt vmcnt(0)" ::: "memory");
    }
    __builtin_amdgcn_s_barrier();      // publish: all waves' tile t in LDS
    __builtin_amdgcn_sched_barrier(0); // reads must not hoist above barrier
    bf16x8 ah[2], al[2], bhf[4], blf[4];
#pragma unroll
    for (int mt = 0; mt < 2; ++mt) {
      ah[mt] = *(const bf16x8*)(&Ash[cur][aOff[mt]]);
      al[mt] = *(const bf16x8*)(&Asl[cur][aOff[mt]]);
    }
#pragma unroll
    for (int nt = 0; nt < 4; ++nt) {
      bhf[nt] = *(const bf16x8*)(&Bsh[cur][bOff[nt]]);
      blf[nt] = *(const bf16x8*)(&Bsl[cur][bOff[nt]]);
    }
#pragma unroll
    for (int mt = 0; mt < 2; ++mt)
#pragma unroll
      for (int nt = 0; nt < 4; ++nt) {
        acc[mt][nt] = MFMA16(ah[mt], bhf[nt], acc[mt][nt]);
        acc[mt][nt] = MFMA16(ah[mt], blf[nt], acc[mt][nt]);
        acc[mt][nt] = MFMA16(al[mt], bhf[nt], acc[mt][nt]);
      }
    asm volatile("s_waitcnt lgkmcnt(0)" ::: "memory");  // my reads retired
    __builtin_amdgcn_s_barrier();  // all reads of buf[cur] done -> overwrite ok
  }

  float* Cf = (float*)(g_ws + (z == 0 ? c0o : c1o));
  bf16_t* Ch = (bf16_t*)(g_ws + c0o);
  bf16_t* Cl = (bf16_t*)(g_ws + c1o);
  bf16_t* VTh = (bf16_t*)(g_ws + OFF_VT_HI);
  bf16_t* VTl = (bf16_t*)(g_ws + OFF_VT_LO);
  const bool vpart = (EPI == 4) && (n0 >= 2048);  // block-uniform
#pragma unroll
  for (int mt = 0; mt < 2; ++mt) {
    const int row0 = m0 + wm * 32 + mt * 16 + quad * 4;
#pragma unroll
    for (int nt = 0; nt < 4; ++nt) {
      const int col = n0 + wn * 64 + nt * 16 + l16;
      float bv = ((EPI == 2 || EPI == 3) && z == 0) ? bias[col] : 0.0f;
      if (vpart) {
        // V third: write transposed into VT[bh][v][s], 4 consecutive s.
        const int bb = row0 >> 10, s0v = row0 & 1023;
        const int hcol = col - 2048, hh8 = hcol >> 7, vv = hcol & 127;
        const long voff = ((long)(bb * 8 + hh8) << 17) + ((long)vv << 10) + s0v;
        bf16x4v hv, lv;
#pragma unroll
        for (int r = 0; r < 4; ++r) {
          bf16_t h, l;
          split2(acc[mt][nt][r], h, l);
          hv[r] = h;
          lv[r] = l;
        }
        *(bf16x4v*)(VTh + voff) = hv;
        *(bf16x4v*)(VTl + voff) = lv;
      } else {
#pragma unroll
        for (int r = 0; r < 4; ++r) {
          float v = acc[mt][nt][r] + bv;
          if (EPI == 2) v = fmaxf(v, 0.0f);
          long off = (long)(row0 + r) * N + col;
          if (EPI == 0 || EPI == 3) {
            Cf[off] = v;
          } else {
            bf16_t h, l;
            split2(v, h, l);
            Ch[off] = h;
            Cl[off] = l;
          }
        }
      }
    }
  }
}

// ---------------------------------------------------------------------------
// Fused attention (flash-style; reference has NO 1/sqrt(dk) scale).
// grid = (S/64 q-tiles, B*H). block 256 (4 waves); wave owns 16 q rows.
// R8 pipeline (proven): stage V; vmcnt(8) [K only]; barA; QK+softmax (V in
// flight); vmcnt(0); barB; stage next K into dead K buf; PV; lgkm(0); barC.
// ---------------------------------------------------------------------------
__global__ __launch_bounds__(256) void attn_kernel(const float* __restrict__ mask) {
  const bf16_t* QKVh = (const bf16_t*)(g_ws + OFF_QKV_HI);
  const bf16_t* QKVl = (const bf16_t*)(g_ws + OFF_QKV_LO);
  const bf16_t* VTh = (const bf16_t*)(g_ws + OFF_VT_HI);
  const bf16_t* VTl = (const bf16_t*)(g_ws + OFF_VT_LO);
  bf16_t* conch = (bf16_t*)(g_ws + OFF_CONC_HI);
  bf16_t* concl = (bf16_t*)(g_ws + OFF_CONC_LO);
  __shared__ __align__(16) bf16_t Ksh[64 * 128];
  __shared__ __align__(16) bf16_t Ksl[64 * 128];
  __shared__ __align__(16) bf16_t Vsh[128 * 64];
  __shared__ __align__(16) bf16_t Vsl[128 * 64];
  __shared__ __align__(16) bf16_t Ps[4][16 * 72];  // P hi, +8 pad per row
  const int tid = threadIdx.x;
  const int wave = tid >> 6, lane = tid & 63;
  const int quad = lane >> 4, l16 = lane & 15;
  const int q0 = blockIdx.x * 64;
  const int bh = blockIdx.y, b = bh >> 3, h = bh & 7;

  bf16x8 qfh[4], qfl[4];
  const long qgbase = ((long)(b * 1024) + q0 + wave * 16 + l16) * 3072 + h * 128;
#pragma unroll
  for (int ks = 0; ks < 4; ++ks) {
    qfh[ks] = *(const bf16x8*)(QKVh + qgbase + ks * 32 + quad * 8);
    qfl[ks] = *(const bf16x8*)(QKVl + qgbase + ks * 32 + quad * 8);
  }

  const int sKrow4 = wave * 16 + (lane >> 4);  // + j*4 = actual row
  const int sVrow = wave * 32 + (lane >> 3);   // + j*8 (row&7 invariant)
  const int sVc = (lane & 7) ^ (sVrow & 7);
  const long vgbase = (long)bh * 131072 + (long)sVrow * 1024 + sVc * 8;

  // staging helpers: 8 gl2lds each per wave
  auto stageK = [&](int tt) {
#pragma unroll
    for (int j = 0; j < 4; ++j) {
      const int r = sKrow4 + j * 4;
      const int c = (lane & 15) ^ ((r & 7) * 2);
      const long kg = ((long)(b * 1024) + tt + r) * 3072 + 1024 + h * 128 + c * 8;
      gl2lds16(QKVh + kg, Ksh + (wave * 16 + j * 4) * 128);
      gl2lds16(QKVl + kg, Ksl + (wave * 16 + j * 4) * 128);
    }
  };
  auto stageV = [&](int tt) {
#pragma unroll
    for (int j = 0; j < 4; ++j) {
      const long vg = vgbase + (long)(j * 8) * 1024 + tt;
      gl2lds16(VTh + vg, Vsh + (wave * 32 + j * 8) * 64);
      gl2lds16(VTl + vg, Vsl + (wave * 32 + j * 8) * 64);
    }
  };

  f32x4 o[8] = {};
  float mi[4] = {-1e30f, -1e30f, -1e30f, -1e30f};
  float li[4] = {0.f, 0.f, 0.f, 0.f};

  stageK(0);  // prologue: K tile 0 in flight (8 loads)

  for (int t0 = 0; t0 < 1024; t0 += 64) {
    stageV(t0);  // V tile in flight (8 loads; K's 8 older)
    asm volatile("s_waitcnt vmcnt(8)" ::: "memory");  // K[t] landed; V flying
    __builtin_amdgcn_s_barrier();       // A: K visible to all waves
    __builtin_amdgcn_sched_barrier(0);  // K reads must not hoist above A
    // ---- S = Q @ K^T (split) ----
    f32x4 s4[4] = {};
#pragma unroll
    for (int nt = 0; nt < 4; ++nt) {
      const int krow = nt * 16 + l16;
      const int ksw = (krow & 7) * 2;
#pragma unroll
      for (int ks = 0; ks < 4; ++ks) {
        const int so = krow * 128 + (((ks * 4 + quad) ^ ksw) * 8);
        bf16x8 kfh = *(const bf16x8*)(Ksh + so);
        bf16x8 kfl = *(const bf16x8*)(Ksl + so);
        s4[nt] = MFMA16(qfh[ks], kfh, s4[nt]);
        s4[nt] = MFMA16(qfh[ks], kfl, s4[nt]);
        s4[nt] = MFMA16(qfl[ks], kfh, s4[nt]);
      }
    }
    // mask + online softmax (V loads still in flight underneath)
#pragma unroll
    for (int nt = 0; nt < 4; ++nt) {
      float mv = mask[b * 1024 + t0 + nt * 16 + l16];
      float addv = (1.0f - mv) * (-1e-30f);
#pragma unroll
      for (int r = 0; r < 4; ++r) s4[nt][r] = mv * s4[nt][r] + addv;
    }
#pragma unroll
    for (int r = 0; r < 4; ++r) {
      float mx = fmaxf(fmaxf(s4[0][r], s4[1][r]), fmaxf(s4[2][r], s4[3][r]));
#pragma unroll
      for (int off = 1; off < 16; off <<= 1) mx = fmaxf(mx, __shfl_xor(mx, off, 64));
      float mnew = fmaxf(mi[r], mx);
      float alpha = __expf(mi[r] - mnew);
      float rs = 0.0f;
#pragma unroll
      for (int nt = 0; nt < 4; ++nt) {
        float p = __expf(s4[nt][r] - mnew);
        s4[nt][r] = p;
        rs += p;
      }
#pragma unroll
      for (int off = 1; off < 16; off <<= 1) rs += __shfl_xor(rs, off, 64);
      li[r] = li[r] * alpha + rs;
      mi[r] = mnew;
#pragma unroll
      for (int on = 0; on < 8; ++on) o[on][r] *= alpha;
    }
    asm volatile("s_waitcnt vmcnt(0)" ::: "memory");  // V[t] (+mask) landed
    __builtin_amdgcn_s_barrier();       // B: V visible; all K reads retired
    __builtin_amdgcn_sched_barrier(0);  // V reads / K-stage must not hoist
    if (t0 + 64 < 1024) stageK(t0 + 64);  // overwrite dead K buffer
    // P: C-layout -> per-wave LDS -> A-layout (DS in-order per wave)
#pragma unroll
    for (int nt = 0; nt < 4; ++nt)
#pragma unroll
      for (int r = 0; r < 4; ++r)
        Ps[wave][(quad * 4 + r) * 72 + nt * 16 + l16] = (bf16_t)s4[nt][r];
    bf16x8 pf[2];
#pragma unroll
    for (int k2 = 0; k2 < 2; ++k2)
      pf[k2] = *(const bf16x8*)(&Ps[wave][l16 * 72 + k2 * 32 + quad * 8]);
    // ---- O += P @ V ----
#pragma unroll
    for (int k2 = 0; k2 < 2; ++k2) {
#pragma unroll
      for (int on = 0; on < 8; ++on) {
        const int vrow = on * 16 + l16;
        const int so = vrow * 64 + (((k2 * 4 + quad) ^ (vrow & 7)) * 8);
        bf16x8 vfh = *(const bf16x8*)(Vsh + so);
        bf16x8 vfl = *(const bf16x8*)(Vsl + so);
        o[on] = MFMA16(pf[k2], vfh, o[on]);
        o[on] = MFMA16(pf[k2], vfl, o[on]);
      }
    }
    asm volatile("s_waitcnt lgkmcnt(0)" ::: "memory");  // my V/P reads retired
    __builtin_amdgcn_s_barrier();       // C: V buffer free for next tile
    __builtin_amdgcn_sched_barrier(0);  // next stageV must not hoist above C
  }
  const int srow_o = q0 + wave * 16 + quad * 4;
#pragma unroll
  for (int r = 0; r < 4; ++r) {
    float inv = 1.0f / li[r];
#pragma unroll
    for (int on = 0; on < 8; ++on) {
      float v = o[on][r] * inv;
      bf16_t hh, ll;
      split2(v, hh, ll);
      long off = (long)(b * 1024 + srow_o + r) * 1024 + h * 128 + on * 16 + l16;
      conch[off] = hh;
      concl[off] = ll;
    }
  }
}

// ---------------------------------------------------------------------------
// Residual + LayerNorm. One block per row (D=1024). Reads X32 + TMP + TMP2
// (split-K partials), writes X32 + split XB; if extf != null (final) writes
// fp32 there instead.
// ---------------------------------------------------------------------------
__global__ __launch_bounds__(256) void ln_kernel(
    const float* __restrict__ gamma, const float* __restrict__ beta, int gidx,
    float* __restrict__ extf) {
  const float* xres = (const float*)(g_ws + OFF_X32);
  const float* y1 = (const float*)(g_ws + OFF_TMP);
  const float* y2 = (const float*)(g_ws + OFF_TMP2);
  float* xout = (float*)(g_ws + OFF_X32);
  bf16_t* xbh = (bf16_t*)(g_ws + OFF_XB_HI);
  bf16_t* xbl = (bf16_t*)(g_ws + OFF_XB_LO);
  const int row = blockIdx.x, tid = threadIdx.x;
  const int wave = tid >> 6, lane = tid & 63;
  const long base = (long)row * 1024 + tid * 4;
  float4 xv = *(const float4*)(xres + base);
  float4 yv = *(const float4*)(y1 + base);
  float4 y2v = *(const float4*)(y2 + base);
  float v0 = xv.x + yv.x + y2v.x, v1 = xv.y + yv.y + y2v.y;
  float v2 = xv.z + yv.z + y2v.z, v3 = xv.w + yv.w + y2v.w;
  float s1 = v0 + v1 + v2 + v3;
  float s2 = v0 * v0 + v1 * v1 + v2 * v2 + v3 * v3;
#pragma unroll
  for (int off = 1; off < 64; off <<= 1) {
    s1 += __shfl_xor(s1, off, 64);
    s2 += __shfl_xor(s2, off, 64);
  }
  __shared__ __align__(16) float r1[4], r2[4];
  if (lane == 0) { r1[wave] = s1; r2[wave] = s2; }
  __syncthreads();
  s1 = r1[0] + r1[1] + r1[2] + r1[3];
  s2 = r2[0] + r2[1] + r2[2] + r2[3];
  const float mean = s1 * (1.0f / 1024.0f);
  float var = s2 * (1.0f / 1024.0f) - mean * mean;
  var = fmaxf(var, 0.0f);
  const float inv = rsqrtf(var + 1e-14f);
  const float g = gamma[gidx], be = beta[gidx];
  float o0 = (v0 - mean) * inv * g + be;
  float o1 = (v1 - mean) * inv * g + be;
  float o2 = (v2 - mean) * inv * g + be;
  float o3 = (v3 - mean) * inv * g + be;
  float4 ov = {o0, o1, o2, o3};
  *(float4*)(xout + base) = ov;
  if (extf) {
    *(float4*)(extf + base) = ov;
  } else {
    bf16_t h0, l0, h1, l1, h2, l2, h3, l3;
    split2(o0, h0, l0); split2(o1, h1, l1);
    split2(o2, h2, l2); split2(o3, h3, l3);
    bf16x4v hv = {h0, h1, h2, h3};
    bf16x4v lv = {l0, l1, l2, l3};
    *(bf16x4v*)(xbh + base) = hv;
    *(bf16x4v*)(xbl + base) = lv;
  }
}

// fp32 input x -> X32 (fp32 copy) + split XB
__global__ __launch_bounds__(256) void cast_f2b(const float* __restrict__ in) {
  float* out = (float*)(g_ws + OFF_X32);
  bf16_t* outh = (bf16_t*)(g_ws + OFF_XB_HI);
  bf16_t* outl = (bf16_t*)(g_ws + OFF_XB_LO);
  long i = ((long)blockIdx.x * 256 + threadIdx.x) * 4;
  float4 v = *(const float4*)(in + i);
  *(float4*)(out + i) = v;
  bf16_t h0, l0, h1, l1, h2, l2, h3, l3;
  split2(v.x, h0, l0); split2(v.y, h1, l1);
  split2(v.z, h2, l2); split2(v.w, h3, l3);
  bf16x4v hv = {h0, h1, h2, h3};
  bf16x4v lv = {l0, l1, l2, l3};
  *(bf16x4v*)(outh + i) = hv;
  *(bf16x4v*)(outl + i) = lv;
}

// tiled transpose+split: out[c*R + r] = split(in[r*C + c]). block (32,8).
__global__ __launch_bounds__(256) void transp_split(
    const float* __restrict__ in, size_t oh_off, size_t ol_off, int R, int C) {
  bf16_t* oh = (bf16_t*)(g_ws + oh_off);
  bf16_t* ol = (bf16_t*)(g_ws + ol_off);
  __shared__ float tile[32][33];
  const int tx = threadIdx.x, ty = threadIdx.y;
  const int c0 = blockIdx.x * 32, r0 = blockIdx.y * 32;
#pragma unroll
  for (int j = 0; j < 4; ++j)
    tile[ty + j * 8][tx] = in[(long)(r0 + ty + j * 8) * C + c0 + tx];
  __syncthreads();
#pragma unroll
  for (int j = 0; j < 4; ++j) {
    float v = tile[tx][ty + j * 8];
    bf16_t h, l;
    split2(v, h, l);
    long off = (long)(c0 + ty + j * 8) * R + r0 + tx;
    oh[off] = h;
    ol[off] = l;
  }
}

// QKV weight repack: Wq/Wk/Wv[h,d,dk] -> WQKV[n = mat*1024 + h*128 + dk][d]
// grid (4, 32, 24): z = mat*8 + h. block (32,8).
__global__ __launch_bounds__(256) void qkvw_trans(
    const float* __restrict__ Wq, const float* __restrict__ Wk,
    const float* __restrict__ Wv) {
  bf16_t* oh = (bf16_t*)(g_ws + OFF_WQKV_HI);
  bf16_t* ol = (bf16_t*)(g_ws + OFF_WQKV_LO);
  __shared__ float tile[32][33];
  const int tx = threadIdx.x, ty = threadIdx.y;
  const int z = blockIdx.z, mat = z >> 3, h = z & 7;
  const float* src = (mat == 0 ? Wq : (mat == 1 ? Wk : Wv)) + h * 131072;
  const int c0 = blockIdx.x * 32, r0 = blockIdx.y * 32;  // c: dk, r: d
#pragma unroll
  for (int j = 0; j < 4; ++j)
    tile[ty + j * 8][tx] = src[(r0 + ty + j * 8) * 128 + c0 + tx];
  __syncthreads();
  const int nbase = mat * 1024 + h * 128;
#pragma unroll
  for (int j = 0; j < 4; ++j) {
    float v = tile[tx][ty + j * 8];
    bf16_t hh, ll;
    split2(v, hh, ll);
    long off = (long)(nbase + c0 + ty + j * 8) * 1024 + r0 + tx;
    oh[off] = hh;
    ol[off] = ll;
  }
}

// ---------------------------------------------------------------------------
extern "C" void kernel_launch(void* const* d_in, const int* in_sizes, int n_in,
                              void* d_out, int out_size, void* d_ws, size_t ws_size,
                              hipStream_t stream) {
  const float* x_in = (const float*)d_in[0];
  const float* mask = (const float*)d_in[1];
  const float* Wq = (const float*)d_in[2];
  const float* Wk = (const float*)d_in[3];
  const float* Wv = (const float*)d_in[4];
  const float* Wo = (const float*)d_in[5];
  const float* W1 = (const float*)d_in[6];
  const float* b1 = (const float*)d_in[7];
  const float* W2 = (const float*)d_in[8];
  const float* b2 = (const float*)d_in[9];
  const float* gamma = (const float*)d_in[10];
  const float* beta = (const float*)d_in[11];
  float* out = (float*)d_out;
  (void)d_ws; (void)ws_size; (void)in_sizes; (void)n_in; (void)out_size;

  const dim3 tb(32, 8);
  cast_f2b<<<4096, 256, 0, stream>>>(x_in);

  for (int l = 0; l < 2; ++l) {
    qkvw_trans<<<dim3(4, 32, 24), tb, 0, stream>>>(
        Wq + (long)l * 1048576, Wk + (long)l * 1048576, Wv + (long)l * 1048576);
    transp_split<<<dim3(32, 32), tb, 0, stream>>>(Wo + (long)l * 1048576,
                                                  OFF_WO_HI, OFF_WO_LO, 1024, 1024);
    transp_split<<<dim3(64, 32), tb, 0, stream>>>(W1 + (long)l * 2097152,
                                                  OFF_W1_HI, OFF_W1_LO, 1024, 2048);
    transp_split<<<dim3(32, 64), tb, 0, stream>>>(W2 + (long)l * 2097152,
                                                  OFF_W2_HI, OFF_W2_LO, 2048, 1024);

    // fused QKV GEMM: [4096,1024] @ [3072,1024]^T -> QKV (Q,K) + VT (V)
    gemm_bt<4><<<dim3(24, 32, 1), 512, 0, stream>>>(
        OFF_XB_HI, OFF_XB_LO, OFF_WQKV_HI, OFF_WQKV_LO,
        OFF_QKV_HI, OFF_QKV_LO, nullptr, 4096, 3072, 1024, 1024);
    attn_kernel<<<dim3(16, 32), 256, 0, stream>>>(mask);
    // proj: split-K2 -> TMP (z=0) + TMP2 (z=1)
    gemm_bt<0><<<dim3(8, 32, 2), 512, 0, stream>>>(
        OFF_CONC_HI, OFF_CONC_LO, OFF_WO_HI, OFF_WO_LO,
        OFF_TMP, OFF_TMP2, nullptr, 4096, 1024, 1024, 512);
    ln_kernel<<<4096, 256, 0, stream>>>(gamma, beta, 2 * l, nullptr);
    gemm_bt<2><<<dim3(16, 32, 1), 512, 0, stream>>>(
        OFF_XB_HI, OFF_XB_LO, OFF_W1_HI, OFF_W1_LO,
        OFF_H_HI, OFF_H_LO, b1 + l * 2048, 4096, 2048, 1024, 1024);
    // ffn2: split-K2 (K=2048) -> TMP + TMP2; bias on slice 0 only
    gemm_bt<3><<<dim3(8, 32, 2), 512, 0, stream>>>(
        OFF_H_HI, OFF_H_LO, OFF_W2_HI, OFF_W2_LO,
        OFF_TMP, OFF_TMP2, b2 + l * 1024, 4096, 1024, 2048, 1024);
    ln_kernel<<<4096, 256, 0, stream>>>(gamma, beta, 2 * l + 1,
                                        (l == 1) ? out : nullptr);
  }
}